// Round 7
// baseline (203.129 us; speedup 1.0000x reference)
//
#include <hip/hip_runtime.h>
#include <hip/hip_bf16.h>

typedef __bf16 bf16_t;
typedef __bf16 bf16x8 __attribute__((ext_vector_type(8)));
typedef __bf16 bf16x4 __attribute__((ext_vector_type(4)));
typedef float  f32x4  __attribute__((ext_vector_type(4)));
typedef float  f32x16 __attribute__((ext_vector_type(16)));
typedef unsigned int u32;
typedef unsigned int u32x2v __attribute__((ext_vector_type(2)));
typedef unsigned int u32x4v __attribute__((ext_vector_type(4)));

#define D_MODEL   1024
#define NQKV      3072
#define NUM_HEADS 16
#define HEAD_DIM  64
#define SEQ       2048
#define BATCH     2
#define NTOK      4096
// 0.125 * log2(e): folded into Q by rope so softmax uses exp2 directly
#define SM_SCALE_LOG2E 0.18033688011112042f
#define NEG_BIG  (-3.0e38f)

// XOR slot swizzle for LDS tiles with 128-byte rows (GEMM staging)
__device__ __forceinline__ int swz128(int row, int bytecol) {
  return row*128 + ((((bytecol>>4) ^ (row&7))<<4) | (bytecol & 15));
}

__device__ __forceinline__ void gload16(const void* g, void* l) {
  __builtin_amdgcn_global_load_lds((const __attribute__((address_space(1))) u32*)g,
                                   (__attribute__((address_space(3))) u32*)l, 16, 0, 0);
}

__device__ __forceinline__ u32 cvtpk_bf16(float a, float b) {
  u32 r;
  asm("v_cvt_pk_bf16_f32 %0, %1, %2" : "=v"(r) : "v"(a), "v"(b));
  return r;
}

// permlane32_swap: res0 = [a.lo | b.lo], res1 = [a.hi | b.hi]
__device__ __forceinline__ void plswap(u32 &a, u32 &b) {
#if __has_builtin(__builtin_amdgcn_permlane32_swap)
  u32x2v r = __builtin_amdgcn_permlane32_swap(a, b, false, false);
  a = r[0]; b = r[1];
#else
  u32 xa = __shfl_xor((unsigned)a, 32, 64);
  u32 xb = __shfl_xor((unsigned)b, 32, 64);
  bool hi = (threadIdx.x & 32) != 0;
  a = hi ? xb : a;
  b = hi ? b : xa;
#endif
}

// slots ordered by descending tile count (longest dispatch first)
__device__ const unsigned char slot_order[48] = {
  15,44,46,47, 14,40,42,43,45, 13,36,38,39,41, 12,32,34,35,37,
  11,28,30,31,33, 10,24,26,27,29, 9,20,22,23,25, 8,16,18,19,21,
  7,17, 6,5,4,3,2,1,0
};

// ---------------- fp32 -> bf16 conversions ----------------
__global__ void cvt_x(const float* __restrict__ in, bf16_t* __restrict__ out) {
  int i = (blockIdx.x*256 + threadIdx.x)*4;
  float4 v = *reinterpret_cast<const float4*>(in + i);
  bf16x4 o; o[0]=(bf16_t)v.x; o[1]=(bf16_t)v.y; o[2]=(bf16_t)v.z; o[3]=(bf16_t)v.w;
  *reinterpret_cast<bf16x4*>(out + i) = o;
}

__global__ void cvt_w(const float* __restrict__ wq, const float* __restrict__ wk,
                      const float* __restrict__ wv, const float* __restrict__ wo,
                      bf16_t* __restrict__ wqkv, bf16_t* __restrict__ wob) {
  const int NW = D_MODEL*D_MODEL;
  int i = (blockIdx.x*256 + threadIdx.x)*4;
  float4 v;
  if      (i <   NW) v = *reinterpret_cast<const float4*>(wq + i);
  else if (i < 2*NW) v = *reinterpret_cast<const float4*>(wk + i - NW);
  else if (i < 3*NW) v = *reinterpret_cast<const float4*>(wv + i - 2*NW);
  else               v = *reinterpret_cast<const float4*>(wo + i - 3*NW);
  bf16x4 o; o[0]=(bf16_t)v.x; o[1]=(bf16_t)v.y; o[2]=(bf16_t)v.z; o[3]=(bf16_t)v.w;
  bf16_t* dst = (i < 3*NW) ? (wqkv + i) : (wob + i - 3*NW);
  *reinterpret_cast<bf16x4*>(dst) = o;
}

// ---------------- RoPE on Q and K inside QKV buffer ----------------
__global__ void rope_qk(bf16_t* __restrict__ QKV, const int* __restrict__ pos) {
  int i = blockIdx.x*256 + threadIdx.x;
  int j = i & 31;
  int hp = (i >> 5) & 15;
  int t  = i >> 9;
  float ang = (float)pos[t & (SEQ-1)] * exp2f(-(float)j * (13.287712379549449f/32.0f));
  float sv, cv; sincosf(ang, &sv, &cv);
  size_t base = (size_t)t*NQKV + hp*64 + 2*j;
  float xe = (float)QKV[base], xo = (float)QKV[base+1];
  QKV[base]   = (bf16_t)((xe*cv - xo*sv)*SM_SCALE_LOG2E);
  QKV[base+1] = (bf16_t)((xe*sv + xo*cv)*SM_SCALE_LOG2E);
  xe = (float)QKV[base+1024]; xo = (float)QKV[base+1025];
  QKV[base+1024] = (bf16_t)(xe*cv - xo*sv);
  QKV[base+1025] = (bf16_t)(xe*sv + xo*cv);
}

// ---------------- GEMM: C[M,N] = A[M,K]*B[N,K]^T (m97-style) ----------------
template<typename OutT, bool QKV>
__global__ __launch_bounds__(256) void gemm_bt(const bf16_t* __restrict__ A,
                                               const bf16_t* __restrict__ B,
                                               OutT* __restrict__ C,
                                               bf16_t* __restrict__ Vt,
                                               int M, int N, int K) {
  __shared__ __align__(16) char lA[128*128];
  __shared__ __align__(16) char lB[128*128];
  int tid = threadIdx.x;
  int n0 = blockIdx.x*128, m0 = blockIdx.y*128;
  int wid = tid>>6, lane = tid&63;
  int wr = wid>>1, wc = wid&1;
  int lr = lane&15, lg = lane>>4;

  const bf16_t* ga = A + (size_t)(m0 + (tid>>3))*K + (tid&7)*8;
  const bf16_t* gb = B + (size_t)(n0 + (tid>>3))*K + (tid&7)*8;
  char* la = lA + tid*16;
  char* lb = lB + tid*16;

  f32x4 acc[4][4];
  #pragma unroll
  for (int a=0;a<4;a++)
    #pragma unroll
    for (int b=0;b<4;b++) acc[a][b] = (f32x4){0.f,0.f,0.f,0.f};

  for (int k0 = 0; k0 < K; k0 += 64) {
    __syncthreads();
    #pragma unroll
    for (int p=0;p<4;p++) {
      gload16(ga + (size_t)p*32*K + k0, la + p*4096);
      gload16(gb + (size_t)p*32*K + k0, lb + p*4096);
    }
    __syncthreads();
    #pragma unroll
    for (int t=0;t<2;t++) {
      bf16x8 af[4], bfr[4];
      #pragma unroll
      for (int mi=0;mi<4;mi++)
        af[mi] = *reinterpret_cast<const bf16x8*>(lA + (wr*64+mi*16+lr)*128 + t*64 + lg*16);
      #pragma unroll
      for (int ni=0;ni<4;ni++)
        bfr[ni] = *reinterpret_cast<const bf16x8*>(lB + (wc*64+ni*16+lr)*128 + t*64 + lg*16);
      #pragma unroll
      for (int mi=0;mi<4;mi++)
        #pragma unroll
        for (int ni=0;ni<4;ni++)
          acc[mi][ni] = __builtin_amdgcn_mfma_f32_16x16x32_bf16(af[mi], bfr[ni], acc[mi][ni], 0, 0, 0);
    }
  }

  if (!QKV || n0 < 2*D_MODEL) {
    #pragma unroll
    for (int mi=0;mi<4;mi++)
      #pragma unroll
      for (int ni=0;ni<4;ni++)
        #pragma unroll
        for (int r=0;r<4;r++) {
          int m = m0 + wr*64 + mi*16 + lg*4 + r;
          int n = n0 + wc*64 + ni*16 + lr;
          C[(size_t)m*N + n] = (OutT)acc[mi][ni][r];
        }
  } else {
    #pragma unroll
    for (int mi=0;mi<4;mi++)
      #pragma unroll
      for (int ni=0;ni<4;ni++)
        #pragma unroll
        for (int r=0;r<4;r++) {
          int m = m0 + wr*64 + mi*16 + lg*4 + r;
          int nl = n0 + wc*64 + ni*16 + lr - 2*D_MODEL;
          int h = nl >> 6, d = nl & 63;
          int bb = m >> 11, s = m & (SEQ-1);
          Vt[(((size_t)(bb*16 + h)*64 + d) << 11) + s] = (bf16_t)acc[mi][ni][r];
        }
  }
}

// ---------------- attention helpers ----------------
__device__ __forceinline__ void load_kv(const bf16_t* kp, const bf16_t* vp,
                                        bf16x8 (&kf)[8], bf16x8 (&vf)[8]) {
  #pragma unroll
  for (int ds=0; ds<4; ds++) {
    kf[ds]   = *reinterpret_cast<const bf16x8*>(kp + ds*16);
    kf[4+ds] = *reinterpret_cast<const bf16x8*>(kp + (size_t)32*NQKV + ds*16);
    vf[ds]   = *reinterpret_cast<const bf16x8*>(vp + ds*16);
    vf[4+ds] = *reinterpret_cast<const bf16x8*>(vp + (size_t)32*SEQ + ds*16);
  }
}

__device__ __forceinline__ void attn_tile(const bf16x8 (&kf)[8], const bf16x8 (&vf)[8],
                                          const bf16x8 (&qf)[4],
                                          f32x16 &O0, f32x16 &O1,
                                          float &mrun, float &lrun,
                                          int k0, int qg, bool diag, int hi) {
  // S^T = K * Q^T
  f32x16 p0 = (f32x16)0.0f, p1 = (f32x16)0.0f;
  __builtin_amdgcn_s_setprio(1);
  #pragma unroll
  for (int ds=0; ds<4; ds++) {
    p0 = __builtin_amdgcn_mfma_f32_32x32x16_bf16(kf[ds],   qf[ds], p0, 0, 0, 0);
    p1 = __builtin_amdgcn_mfma_f32_32x32x16_bf16(kf[4+ds], qf[ds], p1, 0, 0, 0);
  }
  __builtin_amdgcn_s_setprio(0);

  if (diag) {
    #pragma unroll
    for (int r=0; r<16; r++) {
      int kg = k0 + (r&3) + 8*(r>>2) + 4*hi;
      if (kg      > qg) p0[r] = NEG_BIG;
      if (kg + 32 > qg) p1[r] = NEG_BIG;
    }
  }

  // tree row-max
  float mx[8];
  #pragma unroll
  for (int r=0;r<8;r++) mx[r] = fmaxf(fmaxf(p0[r],p0[r+8]), fmaxf(p1[r],p1[r+8]));
  #pragma unroll
  for (int st=4; st>0; st>>=1)
    #pragma unroll
    for (int r=0;r<st;r++) mx[r] = fmaxf(mx[r], mx[r+st]);
  float mt   = fmaxf(mx[0], __shfl_xor(mx[0], 32, 64));
  float mnew = fmaxf(mrun, mt);
  float alpha = exp2f(mrun - mnew);
  #pragma unroll
  for (int r=0; r<16; r++) {
    p0[r] = exp2f(p0[r] - mnew);
    p1[r] = exp2f(p1[r] - mnew);
  }
  // tree row-sum
  float sx[8];
  #pragma unroll
  for (int r=0;r<8;r++) sx[r] = (p0[r]+p0[r+8]) + (p1[r]+p1[r+8]);
  #pragma unroll
  for (int st=4; st>0; st>>=1)
    #pragma unroll
    for (int r=0;r<st;r++) sx[r] += sx[r+st];
  float stot = sx[0] + __shfl_xor(sx[0], 32, 64);
  lrun = lrun*alpha + stot;
  mrun = mnew;
  O0 *= alpha; O1 *= alpha;

  // pack P -> bf16 and redistribute halves (T12)
  u32 pk0[8], pk1[8];
  #pragma unroll
  for (int i2=0; i2<8; i2++) {
    pk0[i2] = cvtpk_bf16(p0[2*i2], p0[2*i2+1]);
    pk1[i2] = cvtpk_bf16(p1[2*i2], p1[2*i2+1]);
  }
  plswap(pk0[0], pk0[2]); plswap(pk0[1], pk0[3]);
  plswap(pk0[4], pk0[6]); plswap(pk0[5], pk0[7]);
  plswap(pk1[0], pk1[2]); plswap(pk1[1], pk1[3]);
  plswap(pk1[4], pk1[6]); plswap(pk1[5], pk1[7]);

  bf16x8 pa[4];
  pa[0] = __builtin_bit_cast(bf16x8, (u32x4v){pk0[0],pk0[1],pk0[2],pk0[3]});
  pa[1] = __builtin_bit_cast(bf16x8, (u32x4v){pk0[4],pk0[5],pk0[6],pk0[7]});
  pa[2] = __builtin_bit_cast(bf16x8, (u32x4v){pk1[0],pk1[1],pk1[2],pk1[3]});
  pa[3] = __builtin_bit_cast(bf16x8, (u32x4v){pk1[4],pk1[5],pk1[6],pk1[7]});

  // O^T += V^T * P^T
  __builtin_amdgcn_s_setprio(1);
  #pragma unroll
  for (int ks=0; ks<4; ks++) {
    O0 = __builtin_amdgcn_mfma_f32_32x32x16_bf16(vf[ks],   pa[ks], O0, 0, 0, 0);
    O1 = __builtin_amdgcn_mfma_f32_32x32x16_bf16(vf[4+ks], pa[ks], O1, 0, 0, 0);
  }
  __builtin_amdgcn_s_setprio(0);
}

// ---------------- Flash causal attention: 1-wave blocks, reg-pipelined ------
// grid (96, B*H), block 64 = ONE wave (no LDS, no barriers). Block bx ->
// (slot s = slot_order[bx>>1], w = bx&1); wave owns q rows qt*64+w*32..+31.
// K/V for tile t+1 are loaded into the alternate register set (A/B static
// naming) BEFORE computing tile t -> global latency hides under compute.
__global__ __launch_bounds__(64, 2) void attn6(const bf16_t* __restrict__ QKV,
                                               const bf16_t* __restrict__ Vt,
                                               bf16_t* __restrict__ pO,
                                               float2* __restrict__ pML) {
  int bh = blockIdx.y;
  int b = bh >> 4, h = bh & 15;
  int lane = threadIdx.x & 63;
  int w = blockIdx.x & 1;
  int q32 = lane & 31, hi = lane >> 5;

  int s = slot_order[blockIdx.x >> 1];
  int qt, t0, t1;
  if (s < 16) { qt = s; t0 = 0; t1 = qt + 1; }
  else {
    int e = s - 16;
    qt = 16 + (e >> 1);
    int n = qt + 1, h0 = (n + 1) >> 1;
    t0 = (e & 1) ? h0 : 0;
    t1 = (e & 1) ? n  : h0;
  }
  int slot = bh*48 + s;

  int qw0 = qt*64 + w*32;
  int qg  = qw0 + q32;

  // Q fragments
  bf16x8 qf[4];
  const bf16_t* qrow = QKV + (size_t)(b*SEQ + qw0 + q32)*NQKV + h*64 + hi*8;
  #pragma unroll
  for (int d=0; d<4; d++) qf[d] = *reinterpret_cast<const bf16x8*>(qrow + d*16);

  // per-lane K/V base pointers
  const bf16_t* kbase = QKV + D_MODEL + (size_t)(b*SEQ + q32)*NQKV + h*64 + hi*8;
  const bf16_t* vbase = Vt + (size_t)bh*64*SEQ + (size_t)q32*SEQ + hi*8;

  f32x16 O0 = (f32x16)0.0f, O1 = (f32x16)0.0f;
  float mrun = NEG_BIG, lrun = 0.f;

  bf16x8 KA[8], VA[8], KB[8], VB[8];
  load_kv(kbase + (size_t)t0*64*NQKV, vbase + t0*64, KA, VA);

  int ti = t0;
  for (;;) {
    // compute A, prefetch into B
    if (ti + 1 < t1)
      load_kv(kbase + (size_t)(ti+1)*64*NQKV, vbase + (ti+1)*64, KB, VB);
    attn_tile(KA, VA, qf, O0, O1, mrun, lrun, ti*64, qg, ti==qt, hi);
    if (++ti >= t1) break;

    // compute B, prefetch into A
    if (ti + 1 < t1)
      load_kv(kbase + (size_t)(ti+1)*64*NQKV, vbase + (ti+1)*64, KA, VA);
    attn_tile(KB, VB, qf, O0, O1, mrun, lrun, ti*64, qg, ti==qt, hi);
    if (++ti >= t1) break;
  }

  // epilogue: write UNNORMALIZED partial O (bf16) + (m,l)
  bf16_t* prow = pO + ((size_t)slot*4096 + (w*32 + q32)*64);
  #pragma unroll
  for (int rg=0; rg<4; rg++) {
    int d0 = 8*rg + 4*hi;
    u32 a0 = cvtpk_bf16(O0[4*rg],   O0[4*rg+1]);
    u32 a1 = cvtpk_bf16(O0[4*rg+2], O0[4*rg+3]);
    *reinterpret_cast<u32x2v*>(prow + d0) = (u32x2v){a0, a1};
    u32 b0 = cvtpk_bf16(O1[4*rg],   O1[4*rg+1]);
    u32 b1 = cvtpk_bf16(O1[4*rg+2], O1[4*rg+3]);
    *reinterpret_cast<u32x2v*>(prow + 32 + d0) = (u32x2v){b0, b1};
  }
  if (hi == 0)
    pML[slot*64 + w*32 + q32] = make_float2(mrun, lrun);
}

// ---------------- combine partials -> Of ----------------
__global__ __launch_bounds__(256) void combine(const bf16_t* __restrict__ pO,
                                               const float2* __restrict__ pML,
                                               bf16_t* __restrict__ Of) {
  int qt = blockIdx.x, bh = blockIdx.y;
  int b = bh >> 4, h = bh & 15;
  int t = threadIdx.x;
  int q = t >> 2, d0 = (t & 3) * 16;
  bf16x8 r0, r1;
  if (qt < 16) {
    int slot = bh*48 + qt;
    float2 ml = pML[slot*64 + q];
    float inv = 1.0f / ml.y;
    const bf16x8* src = reinterpret_cast<const bf16x8*>(pO + (size_t)slot*4096 + q*64 + d0);
    bf16x8 o0 = src[0], o1 = src[1];
    #pragma unroll
    for (int i=0;i<8;i++) {
      r0[i] = (bf16_t)((float)o0[i]*inv);
      r1[i] = (bf16_t)((float)o1[i]*inv);
    }
  } else {
    int s0 = bh*48 + 16 + (qt-16)*2;
    float2 mlA = pML[s0*64 + q];
    float2 mlB = pML[(s0+1)*64 + q];
    float m  = fmaxf(mlA.x, mlB.x);
    float a0 = exp2f(mlA.x - m), a1 = exp2f(mlB.x - m);
    float inv = 1.0f / (a0*mlA.y + a1*mlB.y);
    a0 *= inv; a1 *= inv;
    const bf16x8* sA = reinterpret_cast<const bf16x8*>(pO + (size_t)s0*4096 + q*64 + d0);
    const bf16x8* sB = reinterpret_cast<const bf16x8*>(pO + (size_t)(s0+1)*4096 + q*64 + d0);
    bf16x8 oa0 = sA[0], oa1 = sA[1], ob0 = sB[0], ob1 = sB[1];
    #pragma unroll
    for (int i=0;i<8;i++) {
      r0[i] = (bf16_t)(a0*(float)oa0[i] + a1*(float)ob0[i]);
      r1[i] = (bf16_t)(a0*(float)oa1[i] + a1*(float)ob1[i]);
    }
  }
  bf16x8* dst = reinterpret_cast<bf16x8*>(Of + ((size_t)(b*SEQ) + qt*64 + q)*D_MODEL + h*64 + d0);
  dst[0] = r0; dst[1] = r1;
}

// ---------------- launch ----------------
// Workspace lifetimes:
//   [ 0,  8) MB xb   (phases 1-2)  -> pO head  (attn/combine)
//   [ 8, 14) MB wqkv (phases 1-2)  -> pO tail + pML
//   [14, 16) MB wob  (all phases)
//   [16, 40) MB QKV  (gemm->attn)
//   [40, 48) MB Vtb  (gemm->attn)  -> Of (combine->out-gemm)
extern "C" void kernel_launch(void* const* d_in, const int* in_sizes, int n_in,
                              void* d_out, int out_size, void* d_ws, size_t ws_size,
                              hipStream_t stream) {
  const float* x   = (const float*)d_in[0];
  const int*   pos = (const int*)  d_in[1];
  const float* wq  = (const float*)d_in[2];
  const float* wk  = (const float*)d_in[3];
  const float* wv  = (const float*)d_in[4];
  const float* wo  = (const float*)d_in[5];
  float* out = (float*)d_out;

  char* ws = (char*)d_ws;
  bf16_t* xb   = (bf16_t*)(ws);
  bf16_t* wqkv = (bf16_t*)(ws + ( 8u<<20));
  bf16_t* wob  = (bf16_t*)(ws + (14u<<20));
  bf16_t* QKV  = (bf16_t*)(ws + (16u<<20));
  bf16_t* Vtb  = (bf16_t*)(ws + (40u<<20));
  bf16_t* pO   = (bf16_t*)(ws);                 // 1536*4096*2B = 12 MB
  float2* pML  = (float2*)(ws + (12u<<20));     // 1536*64*8B = 768 KB
  bf16_t* Of   = (bf16_t*)(ws + (40u<<20));     // overlays dead Vtb

  cvt_x<<<NTOK*D_MODEL/1024, 256, 0, stream>>>(x, xb);
  cvt_w<<<4*D_MODEL*D_MODEL/1024, 256, 0, stream>>>(wq, wk, wv, wo, wqkv, wob);

  dim3 gqkv(NQKV/128, NTOK/128);
  gemm_bt<bf16_t, true><<<gqkv, 256, 0, stream>>>(xb, wqkv, QKV, Vtb, NTOK, NQKV, D_MODEL);

  rope_qk<<<NTOK*NUM_HEADS*32/256, 256, 0, stream>>>(QKV, pos);

  dim3 gattn(96, BATCH*NUM_HEADS);
  attn6<<<gattn, 64, 0, stream>>>(QKV, Vtb, pO, pML);

  dim3 gcomb(SEQ/64, BATCH*NUM_HEADS);
  combine<<<gcomb, 256, 0, stream>>>(pO, pML, Of);

  dim3 gout(D_MODEL/128, NTOK/128);
  gemm_bt<float, false><<<gout, 256, 0, stream>>>(Of, wob, out, nullptr, NTOK, D_MODEL, D_MODEL);
}

// Round 8
// 156.921 us; speedup vs baseline: 1.2945x; 1.2945x over previous
//
#include <hip/hip_runtime.h>
#include <hip/hip_bf16.h>

typedef __bf16 bf16_t;
typedef __bf16 bf16x8 __attribute__((ext_vector_type(8)));
typedef __bf16 bf16x4 __attribute__((ext_vector_type(4)));
typedef float  f32x4  __attribute__((ext_vector_type(4)));
typedef float  f32x16 __attribute__((ext_vector_type(16)));
typedef unsigned int u32;
typedef unsigned int u32x2v __attribute__((ext_vector_type(2)));
typedef unsigned int u32x4v __attribute__((ext_vector_type(4)));

#define D_MODEL   1024
#define NQKV      3072
#define NUM_HEADS 16
#define HEAD_DIM  64
#define SEQ       2048
#define BATCH     2
#define NTOK      4096
// 0.125 * log2(e): folded into Q by rope so softmax uses exp2 directly
#define SM_SCALE_LOG2E 0.18033688011112042f
#define NEG_BIG  (-3.0e38f)

// XOR slot swizzle for LDS tiles with 128-byte rows
__device__ __forceinline__ int swz128(int row, int bytecol) {
  return row*128 + ((((bytecol>>4) ^ (row&7))<<4) | (bytecol & 15));
}

__device__ __forceinline__ void gload16(const void* g, void* l) {
  __builtin_amdgcn_global_load_lds((const __attribute__((address_space(1))) u32*)g,
                                   (__attribute__((address_space(3))) u32*)l, 16, 0, 0);
}

__device__ __forceinline__ u32 cvtpk_bf16(float a, float b) {
  u32 r;
  asm("v_cvt_pk_bf16_f32 %0, %1, %2" : "=v"(r) : "v"(a), "v"(b));
  return r;
}

// permlane32_swap: res0 = [a.lo | b.lo], res1 = [a.hi | b.hi]
__device__ __forceinline__ void plswap(u32 &a, u32 &b) {
#if __has_builtin(__builtin_amdgcn_permlane32_swap)
  u32x2v r = __builtin_amdgcn_permlane32_swap(a, b, false, false);
  a = r[0]; b = r[1];
#else
  u32 xa = __shfl_xor((unsigned)a, 32, 64);
  u32 xb = __shfl_xor((unsigned)b, 32, 64);
  bool hi = (threadIdx.x & 32) != 0;
  a = hi ? xb : a;
  b = hi ? b : xa;
#endif
}

// 96 slots/bh: s<32 -> full q-wave s; s>=32 -> e=s-32, qw=32+(e>>1), half e&1.
// Permutation sorted by descending iteration count (longest dispatch first).
__device__ const unsigned char slot_order96[96] = {
  30,31,88,90,92,93,94,95,
  28,29,80,82,84,85,86,87,89,91,
  26,27,72,74,76,77,78,79,81,83,
  24,25,64,66,68,69,70,71,73,75,
  22,23,56,58,60,61,62,63,65,67,
  20,21,48,50,52,53,54,55,57,59,
  18,19,40,42,44,45,46,47,49,51,
  16,17,32,34,36,37,38,39,41,43,
  14,15,33,35,
  12,13, 10,11, 8,9, 6,7, 4,5, 2,3, 0,1
};

// ---------------- fp32 -> bf16 conversions ----------------
__global__ void cvt_x(const float* __restrict__ in, bf16_t* __restrict__ out) {
  int i = (blockIdx.x*256 + threadIdx.x)*4;
  float4 v = *reinterpret_cast<const float4*>(in + i);
  bf16x4 o; o[0]=(bf16_t)v.x; o[1]=(bf16_t)v.y; o[2]=(bf16_t)v.z; o[3]=(bf16_t)v.w;
  *reinterpret_cast<bf16x4*>(out + i) = o;
}

__global__ void cvt_w(const float* __restrict__ wq, const float* __restrict__ wk,
                      const float* __restrict__ wv, const float* __restrict__ wo,
                      bf16_t* __restrict__ wqkv, bf16_t* __restrict__ wob) {
  const int NW = D_MODEL*D_MODEL;
  int i = (blockIdx.x*256 + threadIdx.x)*4;
  float4 v;
  if      (i <   NW) v = *reinterpret_cast<const float4*>(wq + i);
  else if (i < 2*NW) v = *reinterpret_cast<const float4*>(wk + i - NW);
  else if (i < 3*NW) v = *reinterpret_cast<const float4*>(wv + i - 2*NW);
  else               v = *reinterpret_cast<const float4*>(wo + i - 3*NW);
  bf16x4 o; o[0]=(bf16_t)v.x; o[1]=(bf16_t)v.y; o[2]=(bf16_t)v.z; o[3]=(bf16_t)v.w;
  bf16_t* dst = (i < 3*NW) ? (wqkv + i) : (wob + i - 3*NW);
  *reinterpret_cast<bf16x4*>(dst) = o;
}

// ---------------- RoPE on Q and K inside QKV buffer ----------------
__global__ void rope_qk(bf16_t* __restrict__ QKV, const int* __restrict__ pos) {
  int i = blockIdx.x*256 + threadIdx.x;
  int j = i & 31;
  int hp = (i >> 5) & 15;
  int t  = i >> 9;
  float ang = (float)pos[t & (SEQ-1)] * exp2f(-(float)j * (13.287712379549449f/32.0f));
  float sv, cv; sincosf(ang, &sv, &cv);
  size_t base = (size_t)t*NQKV + hp*64 + 2*j;
  float xe = (float)QKV[base], xo = (float)QKV[base+1];
  QKV[base]   = (bf16_t)((xe*cv - xo*sv)*SM_SCALE_LOG2E);
  QKV[base+1] = (bf16_t)((xe*sv + xo*cv)*SM_SCALE_LOG2E);
  xe = (float)QKV[base+1024]; xo = (float)QKV[base+1025];
  QKV[base+1024] = (bf16_t)(xe*cv - xo*sv);
  QKV[base+1025] = (bf16_t)(xe*sv + xo*cv);
}

// ---------------- GEMM: C[M,N] = A[M,K]*B[N,K]^T (m97-style) ----------------
template<typename OutT, bool QKV>
__global__ __launch_bounds__(256) void gemm_bt(const bf16_t* __restrict__ A,
                                               const bf16_t* __restrict__ B,
                                               OutT* __restrict__ C,
                                               bf16_t* __restrict__ Vt,
                                               int M, int N, int K) {
  __shared__ __align__(16) char lA[128*128];
  __shared__ __align__(16) char lB[128*128];
  int tid = threadIdx.x;
  int n0 = blockIdx.x*128, m0 = blockIdx.y*128;
  int wid = tid>>6, lane = tid&63;
  int wr = wid>>1, wc = wid&1;
  int lr = lane&15, lg = lane>>4;

  const bf16_t* ga = A + (size_t)(m0 + (tid>>3))*K + (tid&7)*8;
  const bf16_t* gb = B + (size_t)(n0 + (tid>>3))*K + (tid&7)*8;
  char* la = lA + tid*16;
  char* lb = lB + tid*16;

  f32x4 acc[4][4];
  #pragma unroll
  for (int a=0;a<4;a++)
    #pragma unroll
    for (int b=0;b<4;b++) acc[a][b] = (f32x4){0.f,0.f,0.f,0.f};

  for (int k0 = 0; k0 < K; k0 += 64) {
    __syncthreads();
    #pragma unroll
    for (int p=0;p<4;p++) {
      gload16(ga + (size_t)p*32*K + k0, la + p*4096);
      gload16(gb + (size_t)p*32*K + k0, lb + p*4096);
    }
    __syncthreads();
    #pragma unroll
    for (int t=0;t<2;t++) {
      bf16x8 af[4], bfr[4];
      #pragma unroll
      for (int mi=0;mi<4;mi++)
        af[mi] = *reinterpret_cast<const bf16x8*>(lA + (wr*64+mi*16+lr)*128 + t*64 + lg*16);
      #pragma unroll
      for (int ni=0;ni<4;ni++)
        bfr[ni] = *reinterpret_cast<const bf16x8*>(lB + (wc*64+ni*16+lr)*128 + t*64 + lg*16);
      #pragma unroll
      for (int mi=0;mi<4;mi++)
        #pragma unroll
        for (int ni=0;ni<4;ni++)
          acc[mi][ni] = __builtin_amdgcn_mfma_f32_16x16x32_bf16(af[mi], bfr[ni], acc[mi][ni], 0, 0, 0);
    }
  }

  if (!QKV || n0 < 2*D_MODEL) {
    #pragma unroll
    for (int mi=0;mi<4;mi++)
      #pragma unroll
      for (int ni=0;ni<4;ni++)
        #pragma unroll
        for (int r=0;r<4;r++) {
          int m = m0 + wr*64 + mi*16 + lg*4 + r;
          int n = n0 + wc*64 + ni*16 + lr;
          C[(size_t)m*N + n] = (OutT)acc[mi][ni][r];
        }
  } else {
    #pragma unroll
    for (int mi=0;mi<4;mi++)
      #pragma unroll
      for (int ni=0;ni<4;ni++)
        #pragma unroll
        for (int r=0;r<4;r++) {
          int m = m0 + wr*64 + mi*16 + lg*4 + r;
          int nl = n0 + wc*64 + ni*16 + lr - 2*D_MODEL;
          int h = nl >> 6, d = nl & 63;
          int bb = m >> 11, s = m & (SEQ-1);
          Vt[(((size_t)(bb*16 + h)*64 + d) << 11) + s] = (bf16_t)acc[mi][ni][r];
        }
  }
}

// ---------------- Flash causal attention: 1-wave blocks, counted vmcnt -------
// grid (32 bh, 96 slots), block = ONE wave. No barriers (self-staged LDS).
// K double-buffered (2x8KB), V single-buffered (8KB), re-staged after its
// ds_reads drain. vmcnt(8) per iter keeps next-K in flight (T4).
// bh = blockIdx.x -> fixed XCD per bh -> KV stays L2-resident.
__global__ __launch_bounds__(64, 2) void attn7(const bf16_t* __restrict__ QKV,
                                               const bf16_t* __restrict__ Vt,
                                               bf16_t* __restrict__ pO,
                                               float2* __restrict__ pML) {
  __shared__ __align__(16) char sK[2][64*128];
  __shared__ __align__(16) char sV[64*128];

  int bh = blockIdx.x;
  int b = bh >> 4, h = bh & 15;
  int lane = threadIdx.x & 63;
  int q32 = lane & 31, hi = lane >> 5;
  int rsub = lane >> 3, sg = (lane & 7) ^ rsub;

  int s = slot_order96[blockIdx.y];
  int qw, t0, t1;
  if (s < 32) { qw = s; t0 = 0; t1 = (s >> 1) + 1; }
  else {
    int e = s - 32;
    qw = 32 + (e >> 1);
    int nt = (qw >> 1) + 1, h0 = (nt + 1) >> 1;
    t0 = (e & 1) ? h0 : 0;
    t1 = (e & 1) ? nt : h0;
  }
  int qt   = qw >> 1;              // diagonal kv-tile index
  int slot = bh*96 + s;
  int qg   = qw*32 + q32;

  // Q fragments (loaded before any DMA is issued)
  bf16x8 qf[4];
  const bf16_t* qrow = QKV + (size_t)(b*SEQ + qw*32 + q32)*NQKV + h*64 + hi*8;
  #pragma unroll
  for (int d=0; d<4; d++) qf[d] = *reinterpret_cast<const bf16x8*>(qrow + d*16);

  // per-lane staging sources (inverse-swizzled slot)
  const bf16_t* kgb = QKV + D_MODEL + ((size_t)(b*SEQ) + rsub)*NQKV + h*64 + sg*8;
  const bf16_t* vgb = Vt + (size_t)bh*64*SEQ + (size_t)rsub*SEQ + sg*8;

  auto stageK = [&](int t, int buf) {
    const bf16_t* src = kgb + (size_t)t*64*NQKV;
    #pragma unroll
    for (int c=0;c<8;c++)
      gload16(src + (size_t)(8*c)*NQKV, sK[buf] + c*1024 + lane*16);
  };
  auto stageV = [&](int t) {
    const bf16_t* src = vgb + t*64;
    #pragma unroll
    for (int c=0;c<8;c++)
      gload16(src + (size_t)(8*c)*SEQ, sV + c*1024 + lane*16);
  };

  f32x16 O0 = (f32x16)0.0f, O1 = (f32x16)0.0f;
  float mrun = NEG_BIG, lrun = 0.f;

  stageK(t0, 0); stageV(t0);
  if (t0 + 1 < t1) stageK(t0 + 1, 1);

  for (int ti = t0; ti < t1; ++ti) {
    int cur = (ti - t0) & 1;
    // wait K(ti)+V(ti) landed; leave K(ti+1) (8 newest) in flight if it exists
    if (ti + 1 < t1) { asm volatile("s_waitcnt vmcnt(8)" ::: "memory"); }
    else             { asm volatile("s_waitcnt vmcnt(0)" ::: "memory"); }
    __builtin_amdgcn_sched_barrier(0);

    // S^T = K * Q^T
    bf16x8 k0f[4], k1f[4];
    #pragma unroll
    for (int ds=0; ds<4; ds++) {
      k0f[ds] = *reinterpret_cast<const bf16x8*>(sK[cur] + swz128(q32,    ds*32 + hi*16));
      k1f[ds] = *reinterpret_cast<const bf16x8*>(sK[cur] + swz128(32+q32, ds*32 + hi*16));
    }
    f32x16 p0 = (f32x16)0.0f, p1 = (f32x16)0.0f;
    __builtin_amdgcn_s_setprio(1);
    #pragma unroll
    for (int ds=0; ds<4; ds++) {
      p0 = __builtin_amdgcn_mfma_f32_32x32x16_bf16(k0f[ds], qf[ds], p0, 0, 0, 0);
      p1 = __builtin_amdgcn_mfma_f32_32x32x16_bf16(k1f[ds], qf[ds], p1, 0, 0, 0);
    }
    __builtin_amdgcn_s_setprio(0);

    // causal mask: only the diagonal tile pays
    if (ti == qt) {
      #pragma unroll
      for (int r=0; r<16; r++) {
        int kg = ti*64 + (r&3) + 8*(r>>2) + 4*hi;
        if (kg      > qg) p0[r] = NEG_BIG;
        if (kg + 32 > qg) p1[r] = NEG_BIG;
      }
    }

    // tree row-max
    float mx[8];
    #pragma unroll
    for (int r=0;r<8;r++) mx[r] = fmaxf(fmaxf(p0[r],p0[r+8]), fmaxf(p1[r],p1[r+8]));
    #pragma unroll
    for (int st=4; st>0; st>>=1)
      #pragma unroll
      for (int r=0;r<st;r++) mx[r] = fmaxf(mx[r], mx[r+st]);
    float mt   = fmaxf(mx[0], __shfl_xor(mx[0], 32, 64));
    float mnew = fmaxf(mrun, mt);
    float alpha = exp2f(mrun - mnew);
    #pragma unroll
    for (int r=0; r<16; r++) {
      p0[r] = exp2f(p0[r] - mnew);
      p1[r] = exp2f(p1[r] - mnew);
    }
    // tree row-sum
    float sx[8];
    #pragma unroll
    for (int r=0;r<8;r++) sx[r] = (p0[r]+p0[r+8]) + (p1[r]+p1[r+8]);
    #pragma unroll
    for (int st=4; st>0; st>>=1)
      #pragma unroll
      for (int r=0;r<st;r++) sx[r] += sx[r+st];
    float stot = sx[0] + __shfl_xor(sx[0], 32, 64);
    lrun = lrun*alpha + stot;
    mrun = mnew;
    O0 *= alpha; O1 *= alpha;

    // pack P -> bf16 and redistribute halves (T12)
    u32 pk0[8], pk1[8];
    #pragma unroll
    for (int i2=0; i2<8; i2++) {
      pk0[i2] = cvtpk_bf16(p0[2*i2], p0[2*i2+1]);
      pk1[i2] = cvtpk_bf16(p1[2*i2], p1[2*i2+1]);
    }
    plswap(pk0[0], pk0[2]); plswap(pk0[1], pk0[3]);
    plswap(pk0[4], pk0[6]); plswap(pk0[5], pk0[7]);
    plswap(pk1[0], pk1[2]); plswap(pk1[1], pk1[3]);
    plswap(pk1[4], pk1[6]); plswap(pk1[5], pk1[7]);

    bf16x8 pa[4];
    pa[0] = __builtin_bit_cast(bf16x8, (u32x4v){pk0[0],pk0[1],pk0[2],pk0[3]});
    pa[1] = __builtin_bit_cast(bf16x8, (u32x4v){pk0[4],pk0[5],pk0[6],pk0[7]});
    pa[2] = __builtin_bit_cast(bf16x8, (u32x4v){pk1[0],pk1[1],pk1[2],pk1[3]});
    pa[3] = __builtin_bit_cast(bf16x8, (u32x4v){pk1[4],pk1[5],pk1[6],pk1[7]});

    // V fragments from LDS, then free sV for the next tile's DMA
    bf16x8 v0f[4], v1f[4];
    #pragma unroll
    for (int ks=0; ks<4; ks++) {
      v0f[ks] = *reinterpret_cast<const bf16x8*>(sV + swz128(q32,    ks*32 + hi*16));
      v1f[ks] = *reinterpret_cast<const bf16x8*>(sV + swz128(32+q32, ks*32 + hi*16));
    }
    asm volatile("s_waitcnt lgkmcnt(0)" ::: "memory");
    __builtin_amdgcn_sched_barrier(0);
    if (ti + 1 < t1) stageV(ti + 1);
    if (ti + 2 < t1) stageK(ti + 2, cur);

    // O^T += V^T * P^T
    __builtin_amdgcn_s_setprio(1);
    #pragma unroll
    for (int ks=0; ks<4; ks++) {
      O0 = __builtin_amdgcn_mfma_f32_32x32x16_bf16(v0f[ks], pa[ks], O0, 0, 0, 0);
      O1 = __builtin_amdgcn_mfma_f32_32x32x16_bf16(v1f[ks], pa[ks], O1, 0, 0, 0);
    }
    __builtin_amdgcn_s_setprio(0);
  }

  // epilogue: write UNNORMALIZED partial O (bf16) + (m,l)
  bf16_t* prow = pO + ((size_t)slot*2048 + q32*64);
  #pragma unroll
  for (int rg=0; rg<4; rg++) {
    int d0 = 8*rg + 4*hi;
    u32 a0 = cvtpk_bf16(O0[4*rg],   O0[4*rg+1]);
    u32 a1 = cvtpk_bf16(O0[4*rg+2], O0[4*rg+3]);
    *reinterpret_cast<u32x2v*>(prow + d0) = (u32x2v){a0, a1};
    u32 b0 = cvtpk_bf16(O1[4*rg],   O1[4*rg+1]);
    u32 b1 = cvtpk_bf16(O1[4*rg+2], O1[4*rg+3]);
    *reinterpret_cast<u32x2v*>(prow + 32 + d0) = (u32x2v){b0, b1};
  }
  if (hi == 0)
    pML[slot*32 + q32] = make_float2(mrun, lrun);
}

// ---------------- combine partials -> Of ----------------
// grid (64 qw, 32 bh), 128 thr: q = t>>2 (0..31), d0 = (t&3)*16.
__global__ __launch_bounds__(128) void combine(const bf16_t* __restrict__ pO,
                                               const float2* __restrict__ pML,
                                               bf16_t* __restrict__ Of) {
  int qw = blockIdx.x, bh = blockIdx.y;
  int b = bh >> 4, h = bh & 15;
  int t = threadIdx.x;
  int q = t >> 2, d0 = (t & 3) * 16;
  bf16x8 r0, r1;
  if (qw < 32) {
    int slot = bh*96 + qw;
    float2 ml = pML[slot*32 + q];
    float inv = 1.0f / ml.y;
    const bf16x8* src = reinterpret_cast<const bf16x8*>(pO + (size_t)slot*2048 + q*64 + d0);
    bf16x8 o0 = src[0], o1 = src[1];
    #pragma unroll
    for (int i=0;i<8;i++) {
      r0[i] = (bf16_t)((float)o0[i]*inv);
      r1[i] = (bf16_t)((float)o1[i]*inv);
    }
  } else {
    int s0 = bh*96 + 32 + (qw-32)*2;
    float2 mlA = pML[s0*32 + q];
    float2 mlB = pML[(s0+1)*32 + q];
    float m  = fmaxf(mlA.x, mlB.x);
    float a0 = exp2f(mlA.x - m), a1 = exp2f(mlB.x - m);
    float inv = 1.0f / (a0*mlA.y + a1*mlB.y);
    a0 *= inv; a1 *= inv;
    const bf16x8* sA = reinterpret_cast<const bf16x8*>(pO + (size_t)s0*2048 + q*64 + d0);
    const bf16x8* sB = reinterpret_cast<const bf16x8*>(pO + (size_t)(s0+1)*2048 + q*64 + d0);
    bf16x8 oa0 = sA[0], oa1 = sA[1], ob0 = sB[0], ob1 = sB[1];
    #pragma unroll
    for (int i=0;i<8;i++) {
      r0[i] = (bf16_t)(a0*(float)oa0[i] + a1*(float)ob0[i]);
      r1[i] = (bf16_t)(a0*(float)oa1[i] + a1*(float)ob1[i]);
    }
  }
  bf16x8* dst = reinterpret_cast<bf16x8*>(Of + ((size_t)(b*SEQ) + qw*32 + q)*D_MODEL + h*64 + d0);
  dst[0] = r0; dst[1] = r1;
}

// ---------------- launch ----------------
// Workspace lifetimes:
//   [ 0,  8) MB xb   (phases 1-2)  -> pO head  (attn/combine)
//   [ 8, 14) MB wqkv (phases 1-2)  -> pO tail (to 12.6MB) + pML (at 13MB)
//   [14, 16) MB wob  (all phases)
//   [16, 40) MB QKV  (gemm->attn)
//   [40, 48) MB Vtb  (gemm->attn)  -> Of (combine->out-gemm)
extern "C" void kernel_launch(void* const* d_in, const int* in_sizes, int n_in,
                              void* d_out, int out_size, void* d_ws, size_t ws_size,
                              hipStream_t stream) {
  const float* x   = (const float*)d_in[0];
  const int*   pos = (const int*)  d_in[1];
  const float* wq  = (const float*)d_in[2];
  const float* wk  = (const float*)d_in[3];
  const float* wv  = (const float*)d_in[4];
  const float* wo  = (const float*)d_in[5];
  float* out = (float*)d_out;

  char* ws = (char*)d_ws;
  bf16_t* xb   = (bf16_t*)(ws);
  bf16_t* wqkv = (bf16_t*)(ws + ( 8u<<20));
  bf16_t* wob  = (bf16_t*)(ws + (14u<<20));
  bf16_t* QKV  = (bf16_t*)(ws + (16u<<20));
  bf16_t* Vtb  = (bf16_t*)(ws + (40u<<20));
  bf16_t* pO   = (bf16_t*)(ws);                 // 32*96*2048*2B = 12.6 MB
  float2* pML  = (float2*)(ws + (13u<<20));     // 32*96*32*8B = 768 KB
  bf16_t* Of   = (bf16_t*)(ws + (40u<<20));     // overlays dead Vtb

  cvt_x<<<NTOK*D_MODEL/1024, 256, 0, stream>>>(x, xb);
  cvt_w<<<4*D_MODEL*D_MODEL/1024, 256, 0, stream>>>(wq, wk, wv, wo, wqkv, wob);

  dim3 gqkv(NQKV/128, NTOK/128);
  gemm_bt<bf16_t, true><<<gqkv, 256, 0, stream>>>(xb, wqkv, QKV, Vtb, NTOK, NQKV, D_MODEL);

  rope_qk<<<NTOK*NUM_HEADS*32/256, 256, 0, stream>>>(QKV, pos);

  dim3 gattn(32, 96);
  attn7<<<gattn, 64, 0, stream>>>(QKV, Vtb, pO, pML);

  dim3 gcomb(64, 32);
  combine<<<gcomb, 128, 0, stream>>>(pO, pML, Of);

  dim3 gout(D_MODEL/128, NTOK/128);
  gemm_bt<float, false><<<gout, 256, 0, stream>>>(Of, wob, out, nullptr, NTOK, D_MODEL, D_MODEL);
}

// Round 9
// 135.303 us; speedup vs baseline: 1.5013x; 1.1598x over previous
//
#include <hip/hip_runtime.h>
#include <hip/hip_bf16.h>

typedef __bf16 bf16_t;
typedef __bf16 bf16x8 __attribute__((ext_vector_type(8)));
typedef __bf16 bf16x4 __attribute__((ext_vector_type(4)));
typedef float  f32x4  __attribute__((ext_vector_type(4)));
typedef float  f32x16 __attribute__((ext_vector_type(16)));
typedef unsigned int u32;
typedef unsigned int u32x2v __attribute__((ext_vector_type(2)));
typedef unsigned int u32x4v __attribute__((ext_vector_type(4)));

#define D_MODEL   1024
#define NQKV      3072
#define NUM_HEADS 16
#define HEAD_DIM  64
#define SEQ       2048
#define BATCH     2
#define NTOK      4096
// 0.125 * log2(e): folded into Q by rope so softmax uses exp2 directly
#define SM_SCALE_LOG2E 0.18033688011112042f
#define NEG_BIG  (-3.0e38f)

// XOR slot swizzle for LDS tiles with 128-byte rows
__device__ __forceinline__ int swz128(int row, int bytecol) {
  return row*128 + ((((bytecol>>4) ^ (row&7))<<4) | (bytecol & 15));
}

__device__ __forceinline__ void gload16(const void* g, void* l) {
  __builtin_amdgcn_global_load_lds((const __attribute__((address_space(1))) u32*)g,
                                   (__attribute__((address_space(3))) u32*)l, 16, 0, 0);
}

__device__ __forceinline__ u32 cvtpk_bf16(float a, float b) {
  u32 r;
  asm("v_cvt_pk_bf16_f32 %0, %1, %2" : "=v"(r) : "v"(a), "v"(b));
  return r;
}

// permlane32_swap: res0 = [a.lo | b.lo], res1 = [a.hi | b.hi]
__device__ __forceinline__ void plswap(u32 &a, u32 &b) {
#if __has_builtin(__builtin_amdgcn_permlane32_swap)
  u32x2v r = __builtin_amdgcn_permlane32_swap(a, b, false, false);
  a = r[0]; b = r[1];
#else
  u32 xa = __shfl_xor((unsigned)a, 32, 64);
  u32 xb = __shfl_xor((unsigned)b, 32, 64);
  bool hi = (threadIdx.x & 32) != 0;
  a = hi ? xb : a;
  b = hi ? b : xa;
#endif
}

// 96 slots/bh: s<32 -> full q-wave s; s>=32 -> e=s-32, qw=32+(e>>1), half e&1.
__device__ const unsigned char slot_order96[96] = {
  30,31,88,90,92,93,94,95,
  28,29,80,82,84,85,86,87,89,91,
  26,27,72,74,76,77,78,79,81,83,
  24,25,64,66,68,69,70,71,73,75,
  22,23,56,58,60,61,62,63,65,67,
  20,21,48,50,52,53,54,55,57,59,
  18,19,40,42,44,45,46,47,49,51,
  16,17,32,34,36,37,38,39,41,43,
  14,15,33,35,
  12,13, 10,11, 8,9, 6,7, 4,5, 2,3, 0,1
};

// ---------------- fp32 -> bf16 conversions ----------------
__global__ void cvt_x(const float* __restrict__ in, bf16_t* __restrict__ out) {
  int i = (blockIdx.x*256 + threadIdx.x)*4;
  float4 v = *reinterpret_cast<const float4*>(in + i);
  bf16x4 o; o[0]=(bf16_t)v.x; o[1]=(bf16_t)v.y; o[2]=(bf16_t)v.z; o[3]=(bf16_t)v.w;
  *reinterpret_cast<bf16x4*>(out + i) = o;
}

__global__ void cvt_w(const float* __restrict__ wq, const float* __restrict__ wk,
                      const float* __restrict__ wv, const float* __restrict__ wo,
                      bf16_t* __restrict__ wqkv, bf16_t* __restrict__ wob) {
  const int NW = D_MODEL*D_MODEL;
  int i = (blockIdx.x*256 + threadIdx.x)*4;
  float4 v;
  if      (i <   NW) v = *reinterpret_cast<const float4*>(wq + i);
  else if (i < 2*NW) v = *reinterpret_cast<const float4*>(wk + i - NW);
  else if (i < 3*NW) v = *reinterpret_cast<const float4*>(wv + i - 2*NW);
  else               v = *reinterpret_cast<const float4*>(wo + i - 3*NW);
  bf16x4 o; o[0]=(bf16_t)v.x; o[1]=(bf16_t)v.y; o[2]=(bf16_t)v.z; o[3]=(bf16_t)v.w;
  bf16_t* dst = (i < 3*NW) ? (wqkv + i) : (wob + i - 3*NW);
  *reinterpret_cast<bf16x4*>(dst) = o;
}

// ---------------- RoPE on Q and K inside QKV buffer ----------------
__global__ void rope_qk(bf16_t* __restrict__ QKV, const int* __restrict__ pos) {
  int i = blockIdx.x*256 + threadIdx.x;
  int j = i & 31;
  int hp = (i >> 5) & 15;
  int t  = i >> 9;
  float ang = (float)pos[t & (SEQ-1)] * exp2f(-(float)j * (13.287712379549449f/32.0f));
  float sv, cv; sincosf(ang, &sv, &cv);
  size_t base = (size_t)t*NQKV + hp*64 + 2*j;
  float xe = (float)QKV[base], xo = (float)QKV[base+1];
  QKV[base]   = (bf16_t)((xe*cv - xo*sv)*SM_SCALE_LOG2E);
  QKV[base+1] = (bf16_t)((xe*sv + xo*cv)*SM_SCALE_LOG2E);
  xe = (float)QKV[base+1024]; xo = (float)QKV[base+1025];
  QKV[base+1024] = (bf16_t)(xe*cv - xo*sv);
  QKV[base+1025] = (bf16_t)(xe*sv + xo*cv);
}

// ---------------- GEMM: C[M,N]=A[M,K]*B[N,K]^T — 4-slot counted-vmcnt -------
// 128x128 tile, BK=64, 4 waves. LDS = 4 slots x (A 16KB + B 16KB) = 128 KB.
// Iter t: read slot t&3; stage tile t+2 into slot (t+2)&3 (freed 2 barrier-
// generations ago -> race-free); end-of-iter vmcnt(8) waits tile t+1 only,
// leaving tile t+2's 8 loads in flight (T4). Both LDS sides swizzled (T2):
// inverse-swizzled global source + swz128 ds_read (rule #21). T5 setprio.
template<typename OutT, bool QKV>
__global__ __launch_bounds__(256, 1) void gemm8(const bf16_t* __restrict__ A,
                                                const bf16_t* __restrict__ B,
                                                OutT* __restrict__ C,
                                                bf16_t* __restrict__ Vt,
                                                int M, int N, int K) {
  __shared__ __align__(16) char lds[4][32768];   // per slot: [0,16K)=A, [16K,32K)=B
  int tid = threadIdx.x;
  int n0 = blockIdx.x*128, m0 = blockIdx.y*128;
  int wid = tid>>6, lane = tid&63;
  int wr = wid>>1, wc = wid&1;
  int lr = lane&15, lg = lane>>4;

  const int nT = K >> 6;

  // staging source: thread -> (row_in_group = tid>>3, phys slot = tid&7),
  // fetches logical col8 = (tid&7) ^ (row&7)  (inverse swizzle)
  int srow = tid >> 3;
  int sc8  = (tid & 7) ^ (srow & 7);
  const bf16_t* ga = A + (size_t)(m0 + srow)*K + sc8*8;
  const bf16_t* gb = B + (size_t)(n0 + srow)*K + sc8*8;

  f32x4 acc[4][4];
  #pragma unroll
  for (int a=0;a<4;a++)
    #pragma unroll
    for (int b=0;b<4;b++) acc[a][b] = (f32x4){0.f,0.f,0.f,0.f};

  auto stage = [&](int t) {   // 8 gloads: 4 A-groups then 4 B-groups
    char* s = lds[t&3];
    int k0 = t << 6;
    #pragma unroll
    for (int g=0; g<4; g++)
      gload16(ga + (size_t)(g*32)*K + k0, s + g*4096 + tid*16);
    #pragma unroll
    for (int g=0; g<4; g++)
      gload16(gb + (size_t)(g*32)*K + k0, s + 16384 + g*4096 + tid*16);
  };

  // prologue: tiles 0,1 staged; wait tile 0 (leave tile 1 in flight? no --
  // need vmcnt(8): outstanding 16, oldest 8 = tile 0)
  stage(0);
  if (nT > 1) stage(1);
  asm volatile("s_waitcnt vmcnt(8)" ::: "memory");
  __builtin_amdgcn_sched_barrier(0);
  __builtin_amdgcn_s_barrier();

  for (int t = 0; t < nT; ++t) {
    char* sA = lds[t&3];
    char* sB = sA + 16384;

    // ---- phase 0: B all + A mi0-1; stage t+2; MFMA quadrant {mi0,mi1} ----
    bf16x8 bq[4][2], aq[2][2];
    #pragma unroll
    for (int ni=0; ni<4; ni++)
      #pragma unroll
      for (int ks=0; ks<2; ks++)
        bq[ni][ks] = *reinterpret_cast<const bf16x8*>(sB + swz128(wc*64+ni*16+lr, ks*64+lg*16));
    #pragma unroll
    for (int mi=0; mi<2; mi++)
      #pragma unroll
      for (int ks=0; ks<2; ks++)
        aq[mi][ks] = *reinterpret_cast<const bf16x8*>(sA + swz128(wr*64+mi*16+lr, ks*64+lg*16));
    if (t + 2 < nT) stage(t + 2);
    asm volatile("s_waitcnt lgkmcnt(0)" ::: "memory");
    __builtin_amdgcn_sched_barrier(0);
    __builtin_amdgcn_s_setprio(1);
    #pragma unroll
    for (int mi=0; mi<2; mi++)
      #pragma unroll
      for (int ni=0; ni<4; ni++)
        #pragma unroll
        for (int ks=0; ks<2; ks++)
          acc[mi][ni] = __builtin_amdgcn_mfma_f32_16x16x32_bf16(aq[mi][ks], bq[ni][ks], acc[mi][ni], 0, 0, 0);
    __builtin_amdgcn_s_setprio(0);
    __builtin_amdgcn_s_barrier();

    // ---- phase 1: A mi2-3; MFMA quadrant {mi2,mi3}; counted end-wait ----
    bf16x8 aq2[2][2];
    #pragma unroll
    for (int mi=0; mi<2; mi++)
      #pragma unroll
      for (int ks=0; ks<2; ks++)
        aq2[mi][ks] = *reinterpret_cast<const bf16x8*>(sA + swz128(wr*64+(mi+2)*16+lr, ks*64+lg*16));
    asm volatile("s_waitcnt lgkmcnt(0)" ::: "memory");
    __builtin_amdgcn_sched_barrier(0);
    __builtin_amdgcn_s_setprio(1);
    #pragma unroll
    for (int mi=0; mi<2; mi++)
      #pragma unroll
      for (int ni=0; ni<4; ni++)
        #pragma unroll
        for (int ks=0; ks<2; ks++)
          acc[mi+2][ni] = __builtin_amdgcn_mfma_f32_16x16x32_bf16(aq2[mi][ks], bq[ni][ks], acc[mi+2][ni], 0, 0, 0);
    __builtin_amdgcn_s_setprio(0);
    if (t + 2 < nT)      { asm volatile("s_waitcnt vmcnt(8)" ::: "memory"); }
    else if (t + 1 < nT) { asm volatile("s_waitcnt vmcnt(0)" ::: "memory"); }
    __builtin_amdgcn_sched_barrier(0);
    __builtin_amdgcn_s_barrier();
  }

  if (!QKV || n0 < 2*D_MODEL) {
    #pragma unroll
    for (int mi=0;mi<4;mi++)
      #pragma unroll
      for (int ni=0;ni<4;ni++)
        #pragma unroll
        for (int r=0;r<4;r++) {
          int m = m0 + wr*64 + mi*16 + lg*4 + r;
          int n = n0 + wc*64 + ni*16 + lr;
          C[(size_t)m*N + n] = (OutT)acc[mi][ni][r];
        }
  } else {
    #pragma unroll
    for (int mi=0;mi<4;mi++)
      #pragma unroll
      for (int ni=0;ni<4;ni++)
        #pragma unroll
        for (int r=0;r<4;r++) {
          int m = m0 + wr*64 + mi*16 + lg*4 + r;
          int nl = n0 + wc*64 + ni*16 + lr - 2*D_MODEL;
          int h = nl >> 6, d = nl & 63;
          int bb = m >> 11, s = m & (SEQ-1);
          Vt[(((size_t)(bb*16 + h)*64 + d) << 11) + s] = (bf16_t)acc[mi][ni][r];
        }
  }
}

// ---------------- Flash causal attention: 1-wave blocks, counted vmcnt -------
__global__ __launch_bounds__(64, 2) void attn7(const bf16_t* __restrict__ QKV,
                                               const bf16_t* __restrict__ Vt,
                                               bf16_t* __restrict__ pO,
                                               float2* __restrict__ pML) {
  __shared__ __align__(16) char sK[2][64*128];
  __shared__ __align__(16) char sV[64*128];

  int bh = blockIdx.x;
  int b = bh >> 4, h = bh & 15;
  int lane = threadIdx.x & 63;
  int q32 = lane & 31, hi = lane >> 5;
  int rsub = lane >> 3, sg = (lane & 7) ^ rsub;

  int s = slot_order96[blockIdx.y];
  int qw, t0, t1;
  if (s < 32) { qw = s; t0 = 0; t1 = (s >> 1) + 1; }
  else {
    int e = s - 32;
    qw = 32 + (e >> 1);
    int nt = (qw >> 1) + 1, h0 = (nt + 1) >> 1;
    t0 = (e & 1) ? h0 : 0;
    t1 = (e & 1) ? nt : h0;
  }
  int qt   = qw >> 1;
  int slot = bh*96 + s;
  int qg   = qw*32 + q32;

  bf16x8 qf[4];
  const bf16_t* qrow = QKV + (size_t)(b*SEQ + qw*32 + q32)*NQKV + h*64 + hi*8;
  #pragma unroll
  for (int d=0; d<4; d++) qf[d] = *reinterpret_cast<const bf16x8*>(qrow + d*16);

  const bf16_t* kgb = QKV + D_MODEL + ((size_t)(b*SEQ) + rsub)*NQKV + h*64 + sg*8;
  const bf16_t* vgb = Vt + (size_t)bh*64*SEQ + (size_t)rsub*SEQ + sg*8;

  auto stageK = [&](int t, int buf) {
    const bf16_t* src = kgb + (size_t)t*64*NQKV;
    #pragma unroll
    for (int c=0;c<8;c++)
      gload16(src + (size_t)(8*c)*NQKV, sK[buf] + c*1024 + lane*16);
  };
  auto stageV = [&](int t) {
    const bf16_t* src = vgb + t*64;
    #pragma unroll
    for (int c=0;c<8;c++)
      gload16(src + (size_t)(8*c)*SEQ, sV + c*1024 + lane*16);
  };

  f32x16 O0 = (f32x16)0.0f, O1 = (f32x16)0.0f;
  float mrun = NEG_BIG, lrun = 0.f;

  stageK(t0, 0); stageV(t0);
  if (t0 + 1 < t1) stageK(t0 + 1, 1);

  for (int ti = t0; ti < t1; ++ti) {
    int cur = (ti - t0) & 1;
    if (ti + 1 < t1) { asm volatile("s_waitcnt vmcnt(8)" ::: "memory"); }
    else             { asm volatile("s_waitcnt vmcnt(0)" ::: "memory"); }
    __builtin_amdgcn_sched_barrier(0);

    bf16x8 k0f[4], k1f[4];
    #pragma unroll
    for (int ds=0; ds<4; ds++) {
      k0f[ds] = *reinterpret_cast<const bf16x8*>(sK[cur] + swz128(q32,    ds*32 + hi*16));
      k1f[ds] = *reinterpret_cast<const bf16x8*>(sK[cur] + swz128(32+q32, ds*32 + hi*16));
    }
    f32x16 p0 = (f32x16)0.0f, p1 = (f32x16)0.0f;
    __builtin_amdgcn_s_setprio(1);
    #pragma unroll
    for (int ds=0; ds<4; ds++) {
      p0 = __builtin_amdgcn_mfma_f32_32x32x16_bf16(k0f[ds], qf[ds], p0, 0, 0, 0);
      p1 = __builtin_amdgcn_mfma_f32_32x32x16_bf16(k1f[ds], qf[ds], p1, 0, 0, 0);
    }
    __builtin_amdgcn_s_setprio(0);

    if (ti == qt) {
      #pragma unroll
      for (int r=0; r<16; r++) {
        int kg = ti*64 + (r&3) + 8*(r>>2) + 4*hi;
        if (kg      > qg) p0[r] = NEG_BIG;
        if (kg + 32 > qg) p1[r] = NEG_BIG;
      }
    }

    float mx[8];
    #pragma unroll
    for (int r=0;r<8;r++) mx[r] = fmaxf(fmaxf(p0[r],p0[r+8]), fmaxf(p1[r],p1[r+8]));
    #pragma unroll
    for (int st=4; st>0; st>>=1)
      #pragma unroll
      for (int r=0;r<st;r++) mx[r] = fmaxf(mx[r], mx[r+st]);
    float mt   = fmaxf(mx[0], __shfl_xor(mx[0], 32, 64));
    float mnew = fmaxf(mrun, mt);
    float alpha = exp2f(mrun - mnew);
    #pragma unroll
    for (int r=0; r<16; r++) {
      p0[r] = exp2f(p0[r] - mnew);
      p1[r] = exp2f(p1[r] - mnew);
    }
    float sx[8];
    #pragma unroll
    for (int r=0;r<8;r++) sx[r] = (p0[r]+p0[r+8]) + (p1[r]+p1[r+8]);
    #pragma unroll
    for (int st=4; st>0; st>>=1)
      #pragma unroll
      for (int r=0;r<st;r++) sx[r] += sx[r+st];
    float stot = sx[0] + __shfl_xor(sx[0], 32, 64);
    lrun = lrun*alpha + stot;
    mrun = mnew;
    O0 *= alpha; O1 *= alpha;

    u32 pk0[8], pk1[8];
    #pragma unroll
    for (int i2=0; i2<8; i2++) {
      pk0[i2] = cvtpk_bf16(p0[2*i2], p0[2*i2+1]);
      pk1[i2] = cvtpk_bf16(p1[2*i2], p1[2*i2+1]);
    }
    plswap(pk0[0], pk0[2]); plswap(pk0[1], pk0[3]);
    plswap(pk0[4], pk0[6]); plswap(pk0[5], pk0[7]);
    plswap(pk1[0], pk1[2]); plswap(pk1[1], pk1[3]);
    plswap(pk1[4], pk1[6]); plswap(pk1[5], pk1[7]);

    bf16x8 pa[4];
    pa[0] = __builtin_bit_cast(bf16x8, (u32x4v){pk0[0],pk0[1],pk0[2],pk0[3]});
    pa[1] = __builtin_bit_cast(bf16x8, (u32x4v){pk0[4],pk0[5],pk0[6],pk0[7]});
    pa[2] = __builtin_bit_cast(bf16x8, (u32x4v){pk1[0],pk1[1],pk1[2],pk1[3]});
    pa[3] = __builtin_bit_cast(bf16x8, (u32x4v){pk1[4],pk1[5],pk1[6],pk1[7]});

    bf16x8 v0f[4], v1f[4];
    #pragma unroll
    for (int ks=0; ks<4; ks++) {
      v0f[ks] = *reinterpret_cast<const bf16x8*>(sV + swz128(q32,    ks*32 + hi*16));
      v1f[ks] = *reinterpret_cast<const bf16x8*>(sV + swz128(32+q32, ks*32 + hi*16));
    }
    asm volatile("s_waitcnt lgkmcnt(0)" ::: "memory");
    __builtin_amdgcn_sched_barrier(0);
    if (ti + 1 < t1) stageV(ti + 1);
    if (ti + 2 < t1) stageK(ti + 2, cur);

    __builtin_amdgcn_s_setprio(1);
    #pragma unroll
    for (int ks=0; ks<4; ks++) {
      O0 = __builtin_amdgcn_mfma_f32_32x32x16_bf16(v0f[ks], pa[ks], O0, 0, 0, 0);
      O1 = __builtin_amdgcn_mfma_f32_32x32x16_bf16(v1f[ks], pa[ks], O1, 0, 0, 0);
    }
    __builtin_amdgcn_s_setprio(0);
  }

  bf16_t* prow = pO + ((size_t)slot*2048 + q32*64);
  #pragma unroll
  for (int rg=0; rg<4; rg++) {
    int d0 = 8*rg + 4*hi;
    u32 a0 = cvtpk_bf16(O0[4*rg],   O0[4*rg+1]);
    u32 a1 = cvtpk_bf16(O0[4*rg+2], O0[4*rg+3]);
    *reinterpret_cast<u32x2v*>(prow + d0) = (u32x2v){a0, a1};
    u32 b0 = cvtpk_bf16(O1[4*rg],   O1[4*rg+1]);
    u32 b1 = cvtpk_bf16(O1[4*rg+2], O1[4*rg+3]);
    *reinterpret_cast<u32x2v*>(prow + 32 + d0) = (u32x2v){b0, b1};
  }
  if (hi == 0)
    pML[slot*32 + q32] = make_float2(mrun, lrun);
}

// ---------------- combine partials -> Of ----------------
__global__ __launch_bounds__(128) void combine(const bf16_t* __restrict__ pO,
                                               const float2* __restrict__ pML,
                                               bf16_t* __restrict__ Of) {
  int qw = blockIdx.x, bh = blockIdx.y;
  int b = bh >> 4, h = bh & 15;
  int t = threadIdx.x;
  int q = t >> 2, d0 = (t & 3) * 16;
  bf16x8 r0, r1;
  if (qw < 32) {
    int slot = bh*96 + qw;
    float2 ml = pML[slot*32 + q];
    float inv = 1.0f / ml.y;
    const bf16x8* src = reinterpret_cast<const bf16x8*>(pO + (size_t)slot*2048 + q*64 + d0);
    bf16x8 o0 = src[0], o1 = src[1];
    #pragma unroll
    for (int i=0;i<8;i++) {
      r0[i] = (bf16_t)((float)o0[i]*inv);
      r1[i] = (bf16_t)((float)o1[i]*inv);
    }
  } else {
    int s0 = bh*96 + 32 + (qw-32)*2;
    float2 mlA = pML[s0*32 + q];
    float2 mlB = pML[(s0+1)*32 + q];
    float m  = fmaxf(mlA.x, mlB.x);
    float a0 = exp2f(mlA.x - m), a1 = exp2f(mlB.x - m);
    float inv = 1.0f / (a0*mlA.y + a1*mlB.y);
    a0 *= inv; a1 *= inv;
    const bf16x8* sA = reinterpret_cast<const bf16x8*>(pO + (size_t)s0*2048 + q*64 + d0);
    const bf16x8* sB = reinterpret_cast<const bf16x8*>(pO + (size_t)(s0+1)*2048 + q*64 + d0);
    bf16x8 oa0 = sA[0], oa1 = sA[1], ob0 = sB[0], ob1 = sB[1];
    #pragma unroll
    for (int i=0;i<8;i++) {
      r0[i] = (bf16_t)(a0*(float)oa0[i] + a1*(float)ob0[i]);
      r1[i] = (bf16_t)(a0*(float)oa1[i] + a1*(float)ob1[i]);
    }
  }
  bf16x8* dst = reinterpret_cast<bf16x8*>(Of + ((size_t)(b*SEQ) + qw*32 + q)*D_MODEL + h*64 + d0);
  dst[0] = r0; dst[1] = r1;
}

// ---------------- launch ----------------
// Workspace lifetimes:
//   [ 0,  8) MB xb   (phases 1-2)  -> pO head  (attn/combine)
//   [ 8, 14) MB wqkv (phases 1-2)  -> pO tail (to 12.6MB) + pML (at 13MB)
//   [14, 16) MB wob  (all phases)
//   [16, 40) MB QKV  (gemm->attn)
//   [40, 48) MB Vtb  (gemm->attn)  -> Of (combine->out-gemm)
extern "C" void kernel_launch(void* const* d_in, const int* in_sizes, int n_in,
                              void* d_out, int out_size, void* d_ws, size_t ws_size,
                              hipStream_t stream) {
  const float* x   = (const float*)d_in[0];
  const int*   pos = (const int*)  d_in[1];
  const float* wq  = (const float*)d_in[2];
  const float* wk  = (const float*)d_in[3];
  const float* wv  = (const float*)d_in[4];
  const float* wo  = (const float*)d_in[5];
  float* out = (float*)d_out;

  char* ws = (char*)d_ws;
  bf16_t* xb   = (bf16_t*)(ws);
  bf16_t* wqkv = (bf16_t*)(ws + ( 8u<<20));
  bf16_t* wob  = (bf16_t*)(ws + (14u<<20));
  bf16_t* QKV  = (bf16_t*)(ws + (16u<<20));
  bf16_t* Vtb  = (bf16_t*)(ws + (40u<<20));
  bf16_t* pO   = (bf16_t*)(ws);                 // 32*96*2048*2B = 12.6 MB
  float2* pML  = (float2*)(ws + (13u<<20));     // 32*96*32*8B = 768 KB
  bf16_t* Of   = (bf16_t*)(ws + (40u<<20));     // overlays dead Vtb

  cvt_x<<<NTOK*D_MODEL/1024, 256, 0, stream>>>(x, xb);
  cvt_w<<<4*D_MODEL*D_MODEL/1024, 256, 0, stream>>>(wq, wk, wv, wo, wqkv, wob);

  dim3 gqkv(NQKV/128, NTOK/128);
  gemm8<bf16_t, true><<<gqkv, 256, 0, stream>>>(xb, wqkv, QKV, Vtb, NTOK, NQKV, D_MODEL);

  rope_qk<<<NTOK*NUM_HEADS*32/256, 256, 0, stream>>>(QKV, pos);

  dim3 gattn(32, 96);
  attn7<<<gattn, 64, 0, stream>>>(QKV, Vtb, pO, pML);

  dim3 gcomb(64, 32);
  combine<<<gcomb, 128, 0, stream>>>(pO, pML, Of);

  dim3 gout(D_MODEL/128, NTOK/128);
  gemm8<float, false><<<gout, 256, 0, stream>>>(Of, wob, out, nullptr, NTOK, D_MODEL, D_MODEL);
}

// Round 10
// 131.313 us; speedup vs baseline: 1.5469x; 1.0304x over previous
//
#include <hip/hip_runtime.h>
#include <hip/hip_bf16.h>

typedef __bf16 bf16_t;
typedef __bf16 bf16x8 __attribute__((ext_vector_type(8)));
typedef __bf16 bf16x4 __attribute__((ext_vector_type(4)));
typedef float  f32x4  __attribute__((ext_vector_type(4)));
typedef float  f32x16 __attribute__((ext_vector_type(16)));
typedef unsigned int u32;
typedef unsigned int u32x2v __attribute__((ext_vector_type(2)));
typedef unsigned int u32x4v __attribute__((ext_vector_type(4)));

#define D_MODEL   1024
#define NQKV      3072
#define NUM_HEADS 16
#define HEAD_DIM  64
#define SEQ       2048
#define BATCH     2
#define NTOK      4096
// 0.125 * log2(e): folded into Q by rope so softmax uses exp2 directly
#define SM_SCALE_LOG2E 0.18033688011112042f
#define NEG_BIG  (-3.0e38f)

// XOR slot swizzle for LDS tiles with 128-byte rows
__device__ __forceinline__ int swz128(int row, int bytecol) {
  return row*128 + ((((bytecol>>4) ^ (row&7))<<4) | (bytecol & 15));
}

__device__ __forceinline__ void gload16(const void* g, void* l) {
  __builtin_amdgcn_global_load_lds((const __attribute__((address_space(1))) u32*)g,
                                   (__attribute__((address_space(3))) u32*)l, 16, 0, 0);
}

__device__ __forceinline__ u32 cvtpk_bf16(float a, float b) {
  u32 r;
  asm("v_cvt_pk_bf16_f32 %0, %1, %2" : "=v"(r) : "v"(a), "v"(b));
  return r;
}

// permlane32_swap: res0 = [a.lo | b.lo], res1 = [a.hi | b.hi]
__device__ __forceinline__ void plswap(u32 &a, u32 &b) {
#if __has_builtin(__builtin_amdgcn_permlane32_swap)
  u32x2v r = __builtin_amdgcn_permlane32_swap(a, b, false, false);
  a = r[0]; b = r[1];
#else
  u32 xa = __shfl_xor((unsigned)a, 32, 64);
  u32 xb = __shfl_xor((unsigned)b, 32, 64);
  bool hi = (threadIdx.x & 32) != 0;
  a = hi ? xb : a;
  b = hi ? b : xa;
#endif
}

// 96 slots/bh: s<32 -> full q-wave s; s>=32 -> e=s-32, qw=32+(e>>1), half e&1.
__device__ const unsigned char slot_order96[96] = {
  30,31,88,90,92,93,94,95,
  28,29,80,82,84,85,86,87,89,91,
  26,27,72,74,76,77,78,79,81,83,
  24,25,64,66,68,69,70,71,73,75,
  22,23,56,58,60,61,62,63,65,67,
  20,21,48,50,52,53,54,55,57,59,
  18,19,40,42,44,45,46,47,49,51,
  16,17,32,34,36,37,38,39,41,43,
  14,15,33,35,
  12,13, 10,11, 8,9, 6,7, 4,5, 2,3, 0,1
};

// ---------------- fp32 -> bf16 conversions ----------------
__global__ void cvt_x(const float* __restrict__ in, bf16_t* __restrict__ out) {
  int i = (blockIdx.x*256 + threadIdx.x)*4;
  float4 v = *reinterpret_cast<const float4*>(in + i);
  bf16x4 o; o[0]=(bf16_t)v.x; o[1]=(bf16_t)v.y; o[2]=(bf16_t)v.z; o[3]=(bf16_t)v.w;
  *reinterpret_cast<bf16x4*>(out + i) = o;
}

__global__ void cvt_w(const float* __restrict__ wq, const float* __restrict__ wk,
                      const float* __restrict__ wv, const float* __restrict__ wo,
                      bf16_t* __restrict__ wqkv, bf16_t* __restrict__ wob) {
  const int NW = D_MODEL*D_MODEL;
  int i = (blockIdx.x*256 + threadIdx.x)*4;
  float4 v;
  if      (i <   NW) v = *reinterpret_cast<const float4*>(wq + i);
  else if (i < 2*NW) v = *reinterpret_cast<const float4*>(wk + i - NW);
  else if (i < 3*NW) v = *reinterpret_cast<const float4*>(wv + i - 2*NW);
  else               v = *reinterpret_cast<const float4*>(wo + i - 3*NW);
  bf16x4 o; o[0]=(bf16_t)v.x; o[1]=(bf16_t)v.y; o[2]=(bf16_t)v.z; o[3]=(bf16_t)v.w;
  bf16_t* dst = (i < 3*NW) ? (wqkv + i) : (wob + i - 3*NW);
  *reinterpret_cast<bf16x4*>(dst) = o;
}

// ---------------- RoPE on Q and K inside QKV buffer ----------------
__global__ void rope_qk(bf16_t* __restrict__ QKV, const int* __restrict__ pos) {
  int i = blockIdx.x*256 + threadIdx.x;
  int j = i & 31;
  int hp = (i >> 5) & 15;
  int t  = i >> 9;
  float ang = (float)pos[t & (SEQ-1)] * exp2f(-(float)j * (13.287712379549449f/32.0f));
  float sv, cv; sincosf(ang, &sv, &cv);
  size_t base = (size_t)t*NQKV + hp*64 + 2*j;
  float xe = (float)QKV[base], xo = (float)QKV[base+1];
  QKV[base]   = (bf16_t)((xe*cv - xo*sv)*SM_SCALE_LOG2E);
  QKV[base+1] = (bf16_t)((xe*sv + xo*cv)*SM_SCALE_LOG2E);
  xe = (float)QKV[base+1024]; xo = (float)QKV[base+1025];
  QKV[base+1024] = (bf16_t)(xe*cv - xo*sv);
  QKV[base+1025] = (bf16_t)(xe*sv + xo*cv);
}

// ---------------- GEMM: C[M,N]=A[M,K]*B[N,K]^T — 4-slot counted-vmcnt -------
template<typename OutT, bool QKV>
__global__ __launch_bounds__(256, 1) void gemm8(const bf16_t* __restrict__ A,
                                                const bf16_t* __restrict__ B,
                                                OutT* __restrict__ C,
                                                bf16_t* __restrict__ Vt,
                                                int M, int N, int K) {
  __shared__ __align__(16) char lds[4][32768];   // per slot: [0,16K)=A, [16K,32K)=B
  int tid = threadIdx.x;
  int n0 = blockIdx.x*128, m0 = blockIdx.y*128;
  int wid = tid>>6, lane = tid&63;
  int wr = wid>>1, wc = wid&1;
  int lr = lane&15, lg = lane>>4;

  const int nT = K >> 6;

  int srow = tid >> 3;
  int sc8  = (tid & 7) ^ (srow & 7);
  const bf16_t* ga = A + (size_t)(m0 + srow)*K + sc8*8;
  const bf16_t* gb = B + (size_t)(n0 + srow)*K + sc8*8;

  f32x4 acc[4][4];
  #pragma unroll
  for (int a=0;a<4;a++)
    #pragma unroll
    for (int b=0;b<4;b++) acc[a][b] = (f32x4){0.f,0.f,0.f,0.f};

  auto stage = [&](int t) {
    char* s = lds[t&3];
    int k0 = t << 6;
    #pragma unroll
    for (int g=0; g<4; g++)
      gload16(ga + (size_t)(g*32)*K + k0, s + g*4096 + tid*16);
    #pragma unroll
    for (int g=0; g<4; g++)
      gload16(gb + (size_t)(g*32)*K + k0, s + 16384 + g*4096 + tid*16);
  };

  stage(0);
  if (nT > 1) stage(1);
  asm volatile("s_waitcnt vmcnt(8)" ::: "memory");
  __builtin_amdgcn_sched_barrier(0);
  __builtin_amdgcn_s_barrier();

  for (int t = 0; t < nT; ++t) {
    char* sA = lds[t&3];
    char* sB = sA + 16384;

    bf16x8 bq[4][2], aq[2][2];
    #pragma unroll
    for (int ni=0; ni<4; ni++)
      #pragma unroll
      for (int ks=0; ks<2; ks++)
        bq[ni][ks] = *reinterpret_cast<const bf16x8*>(sB + swz128(wc*64+ni*16+lr, ks*64+lg*16));
    #pragma unroll
    for (int mi=0; mi<2; mi++)
      #pragma unroll
      for (int ks=0; ks<2; ks++)
        aq[mi][ks] = *reinterpret_cast<const bf16x8*>(sA + swz128(wr*64+mi*16+lr, ks*64+lg*16));
    if (t + 2 < nT) stage(t + 2);
    asm volatile("s_waitcnt lgkmcnt(0)" ::: "memory");
    __builtin_amdgcn_sched_barrier(0);
    __builtin_amdgcn_s_setprio(1);
    #pragma unroll
    for (int mi=0; mi<2; mi++)
      #pragma unroll
      for (int ni=0; ni<4; ni++)
        #pragma unroll
        for (int ks=0; ks<2; ks++)
          acc[mi][ni] = __builtin_amdgcn_mfma_f32_16x16x32_bf16(aq[mi][ks], bq[ni][ks], acc[mi][ni], 0, 0, 0);
    __builtin_amdgcn_s_setprio(0);
    __builtin_amdgcn_s_barrier();

    bf16x8 aq2[2][2];
    #pragma unroll
    for (int mi=0; mi<2; mi++)
      #pragma unroll
      for (int ks=0; ks<2; ks++)
        aq2[mi][ks] = *reinterpret_cast<const bf16x8*>(sA + swz128(wr*64+(mi+2)*16+lr, ks*64+lg*16));
    asm volatile("s_waitcnt lgkmcnt(0)" ::: "memory");
    __builtin_amdgcn_sched_barrier(0);
    __builtin_amdgcn_s_setprio(1);
    #pragma unroll
    for (int mi=0; mi<2; mi++)
      #pragma unroll
      for (int ni=0; ni<4; ni++)
        #pragma unroll
        for (int ks=0; ks<2; ks++)
          acc[mi+2][ni] = __builtin_amdgcn_mfma_f32_16x16x32_bf16(aq2[mi][ks], bq[ni][ks], acc[mi+2][ni], 0, 0, 0);
    __builtin_amdgcn_s_setprio(0);
    if (t + 2 < nT)      { asm volatile("s_waitcnt vmcnt(8)" ::: "memory"); }
    else if (t + 1 < nT) { asm volatile("s_waitcnt vmcnt(0)" ::: "memory"); }
    __builtin_amdgcn_sched_barrier(0);
    __builtin_amdgcn_s_barrier();
  }

  if (!QKV || n0 < 2*D_MODEL) {
    #pragma unroll
    for (int mi=0;mi<4;mi++)
      #pragma unroll
      for (int ni=0;ni<4;ni++)
        #pragma unroll
        for (int r=0;r<4;r++) {
          int m = m0 + wr*64 + mi*16 + lg*4 + r;
          int n = n0 + wc*64 + ni*16 + lr;
          C[(size_t)m*N + n] = (OutT)acc[mi][ni][r];
        }
  } else {
    #pragma unroll
    for (int mi=0;mi<4;mi++)
      #pragma unroll
      for (int ni=0;ni<4;ni++)
        #pragma unroll
        for (int r=0;r<4;r++) {
          int m = m0 + wr*64 + mi*16 + lg*4 + r;
          int nl = n0 + wc*64 + ni*16 + lr - 2*D_MODEL;
          int h = nl >> 6, d = nl & 63;
          int bb = m >> 11, s = m & (SEQ-1);
          Vt[(((size_t)(bb*16 + h)*64 + d) << 11) + s] = (bf16_t)acc[mi][ni][r];
        }
  }
}

// ---------------- Flash causal attention: 1-wave, single-buffered K+V -------
// grid (32 bh, 96 slots), block = ONE wave, no barriers. LDS 16 KB (K 8 + V 8)
// -> 10 blocks/CU. Per iter: ds_read ALL K,V frags to regs, lgkmcnt(0), then
// re-stage K(t+1),V(t+1) into the same buffers -> prefetch window = full
// iteration; end-of-iter vmcnt(0) is fully aged (~free).
__global__ __launch_bounds__(64, 2) void attn9(const bf16_t* __restrict__ QKV,
                                               const bf16_t* __restrict__ Vt,
                                               bf16_t* __restrict__ pO,
                                               float2* __restrict__ pML) {
  __shared__ __align__(16) char sK[64*128];
  __shared__ __align__(16) char sV[64*128];

  int bh = blockIdx.x;
  int b = bh >> 4, h = bh & 15;
  int lane = threadIdx.x & 63;
  int q32 = lane & 31, hi = lane >> 5;
  int rsub = lane >> 3, sg = (lane & 7) ^ rsub;

  int s = slot_order96[blockIdx.y];
  int qw, t0, t1;
  if (s < 32) { qw = s; t0 = 0; t1 = (s >> 1) + 1; }
  else {
    int e = s - 32;
    qw = 32 + (e >> 1);
    int nt = (qw >> 1) + 1, h0 = (nt + 1) >> 1;
    t0 = (e & 1) ? h0 : 0;
    t1 = (e & 1) ? nt : h0;
  }
  int qt   = qw >> 1;
  int slot = bh*96 + s;
  int qg   = qw*32 + q32;

  bf16x8 qf[4];
  const bf16_t* qrow = QKV + (size_t)(b*SEQ + qw*32 + q32)*NQKV + h*64 + hi*8;
  #pragma unroll
  for (int d=0; d<4; d++) qf[d] = *reinterpret_cast<const bf16x8*>(qrow + d*16);

  const bf16_t* kgb = QKV + D_MODEL + ((size_t)(b*SEQ) + rsub)*NQKV + h*64 + sg*8;
  const bf16_t* vgb = Vt + (size_t)bh*64*SEQ + (size_t)rsub*SEQ + sg*8;

  auto stageK = [&](int t) {
    const bf16_t* src = kgb + (size_t)t*64*NQKV;
    #pragma unroll
    for (int c=0;c<8;c++)
      gload16(src + (size_t)(8*c)*NQKV, sK + c*1024 + lane*16);
  };
  auto stageV = [&](int t) {
    const bf16_t* src = vgb + t*64;
    #pragma unroll
    for (int c=0;c<8;c++)
      gload16(src + (size_t)(8*c)*SEQ, sV + c*1024 + lane*16);
  };

  f32x16 O0 = (f32x16)0.0f, O1 = (f32x16)0.0f;
  float mrun = NEG_BIG, lrun = 0.f;

  stageK(t0); stageV(t0);
  asm volatile("s_waitcnt vmcnt(0)" ::: "memory");
  __builtin_amdgcn_sched_barrier(0);

  for (int ti = t0; ti < t1; ++ti) {
    // read ALL K,V fragments to registers, then free the buffers
    bf16x8 k0f[4], k1f[4], v0f[4], v1f[4];
    #pragma unroll
    for (int ds=0; ds<4; ds++) {
      k0f[ds] = *reinterpret_cast<const bf16x8*>(sK + swz128(q32,    ds*32 + hi*16));
      k1f[ds] = *reinterpret_cast<const bf16x8*>(sK + swz128(32+q32, ds*32 + hi*16));
      v0f[ds] = *reinterpret_cast<const bf16x8*>(sV + swz128(q32,    ds*32 + hi*16));
      v1f[ds] = *reinterpret_cast<const bf16x8*>(sV + swz128(32+q32, ds*32 + hi*16));
    }
    asm volatile("s_waitcnt lgkmcnt(0)" ::: "memory");
    __builtin_amdgcn_sched_barrier(0);
    // re-stage next tile into the same buffers; lands by end of this iter
    if (ti + 1 < t1) { stageK(ti + 1); stageV(ti + 1); }

    // S^T = K * Q^T
    f32x16 p0 = (f32x16)0.0f, p1 = (f32x16)0.0f;
    __builtin_amdgcn_s_setprio(1);
    #pragma unroll
    for (int ds=0; ds<4; ds++) {
      p0 = __builtin_amdgcn_mfma_f32_32x32x16_bf16(k0f[ds], qf[ds], p0, 0, 0, 0);
      p1 = __builtin_amdgcn_mfma_f32_32x32x16_bf16(k1f[ds], qf[ds], p1, 0, 0, 0);
    }
    __builtin_amdgcn_s_setprio(0);

    if (ti == qt) {
      #pragma unroll
      for (int r=0; r<16; r++) {
        int kg = ti*64 + (r&3) + 8*(r>>2) + 4*hi;
        if (kg      > qg) p0[r] = NEG_BIG;
        if (kg + 32 > qg) p1[r] = NEG_BIG;
      }
    }

    float mx[8];
    #pragma unroll
    for (int r=0;r<8;r++) mx[r] = fmaxf(fmaxf(p0[r],p0[r+8]), fmaxf(p1[r],p1[r+8]));
    #pragma unroll
    for (int st=4; st>0; st>>=1)
      #pragma unroll
      for (int r=0;r<st;r++) mx[r] = fmaxf(mx[r], mx[r+st]);
    float mt   = fmaxf(mx[0], __shfl_xor(mx[0], 32, 64));
    float mnew = fmaxf(mrun, mt);
    float alpha = exp2f(mrun - mnew);
    #pragma unroll
    for (int r=0; r<16; r++) {
      p0[r] = exp2f(p0[r] - mnew);
      p1[r] = exp2f(p1[r] - mnew);
    }
    float sx[8];
    #pragma unroll
    for (int r=0;r<8;r++) sx[r] = (p0[r]+p0[r+8]) + (p1[r]+p1[r+8]);
    #pragma unroll
    for (int st=4; st>0; st>>=1)
      #pragma unroll
      for (int r=0;r<st;r++) sx[r] += sx[r+st];
    float stot = sx[0] + __shfl_xor(sx[0], 32, 64);
    lrun = lrun*alpha + stot;
    mrun = mnew;
    O0 *= alpha; O1 *= alpha;

    u32 pk0[8], pk1[8];
    #pragma unroll
    for (int i2=0; i2<8; i2++) {
      pk0[i2] = cvtpk_bf16(p0[2*i2], p0[2*i2+1]);
      pk1[i2] = cvtpk_bf16(p1[2*i2], p1[2*i2+1]);
    }
    plswap(pk0[0], pk0[2]); plswap(pk0[1], pk0[3]);
    plswap(pk0[4], pk0[6]); plswap(pk0[5], pk0[7]);
    plswap(pk1[0], pk1[2]); plswap(pk1[1], pk1[3]);
    plswap(pk1[4], pk1[6]); plswap(pk1[5], pk1[7]);

    bf16x8 pa[4];
    pa[0] = __builtin_bit_cast(bf16x8, (u32x4v){pk0[0],pk0[1],pk0[2],pk0[3]});
    pa[1] = __builtin_bit_cast(bf16x8, (u32x4v){pk0[4],pk0[5],pk0[6],pk0[7]});
    pa[2] = __builtin_bit_cast(bf16x8, (u32x4v){pk1[0],pk1[1],pk1[2],pk1[3]});
    pa[3] = __builtin_bit_cast(bf16x8, (u32x4v){pk1[4],pk1[5],pk1[6],pk1[7]});

    // O^T += V^T * P^T
    __builtin_amdgcn_s_setprio(1);
    #pragma unroll
    for (int ks=0; ks<4; ks++) {
      O0 = __builtin_amdgcn_mfma_f32_32x32x16_bf16(v0f[ks], pa[ks], O0, 0, 0, 0);
      O1 = __builtin_amdgcn_mfma_f32_32x32x16_bf16(v1f[ks], pa[ks], O1, 0, 0, 0);
    }
    __builtin_amdgcn_s_setprio(0);

    // prefetch (issued ~a full iteration ago) must be in LDS before next read
    if (ti + 1 < t1) {
      asm volatile("s_waitcnt vmcnt(0)" ::: "memory");
      __builtin_amdgcn_sched_barrier(0);
    }
  }

  bf16_t* prow = pO + ((size_t)slot*2048 + q32*64);
  #pragma unroll
  for (int rg=0; rg<4; rg++) {
    int d0 = 8*rg + 4*hi;
    u32 a0 = cvtpk_bf16(O0[4*rg],   O0[4*rg+1]);
    u32 a1 = cvtpk_bf16(O0[4*rg+2], O0[4*rg+3]);
    *reinterpret_cast<u32x2v*>(prow + d0) = (u32x2v){a0, a1};
    u32 b0 = cvtpk_bf16(O1[4*rg],   O1[4*rg+1]);
    u32 b1 = cvtpk_bf16(O1[4*rg+2], O1[4*rg+3]);
    *reinterpret_cast<u32x2v*>(prow + 32 + d0) = (u32x2v){b0, b1};
  }
  if (hi == 0)
    pML[slot*32 + q32] = make_float2(mrun, lrun);
}

// ---------------- combine partials -> Of ----------------
__global__ __launch_bounds__(128) void combine(const bf16_t* __restrict__ pO,
                                               const float2* __restrict__ pML,
                                               bf16_t* __restrict__ Of) {
  int qw = blockIdx.x, bh = blockIdx.y;
  int b = bh >> 4, h = bh & 15;
  int t = threadIdx.x;
  int q = t >> 2, d0 = (t & 3) * 16;
  bf16x8 r0, r1;
  if (qw < 32) {
    int slot = bh*96 + qw;
    float2 ml = pML[slot*32 + q];
    float inv = 1.0f / ml.y;
    const bf16x8* src = reinterpret_cast<const bf16x8*>(pO + (size_t)slot*2048 + q*64 + d0);
    bf16x8 o0 = src[0], o1 = src[1];
    #pragma unroll
    for (int i=0;i<8;i++) {
      r0[i] = (bf16_t)((float)o0[i]*inv);
      r1[i] = (bf16_t)((float)o1[i]*inv);
    }
  } else {
    int s0 = bh*96 + 32 + (qw-32)*2;
    float2 mlA = pML[s0*32 + q];
    float2 mlB = pML[(s0+1)*32 + q];
    float m  = fmaxf(mlA.x, mlB.x);
    float a0 = exp2f(mlA.x - m), a1 = exp2f(mlB.x - m);
    float inv = 1.0f / (a0*mlA.y + a1*mlB.y);
    a0 *= inv; a1 *= inv;
    const bf16x8* sA = reinterpret_cast<const bf16x8*>(pO + (size_t)s0*2048 + q*64 + d0);
    const bf16x8* sB = reinterpret_cast<const bf16x8*>(pO + (size_t)(s0+1)*2048 + q*64 + d0);
    bf16x8 oa0 = sA[0], oa1 = sA[1], ob0 = sB[0], ob1 = sB[1];
    #pragma unroll
    for (int i=0;i<8;i++) {
      r0[i] = (bf16_t)(a0*(float)oa0[i] + a1*(float)ob0[i]);
      r1[i] = (bf16_t)(a0*(float)oa1[i] + a1*(float)ob1[i]);
    }
  }
  bf16x8* dst = reinterpret_cast<bf16x8*>(Of + ((size_t)(b*SEQ) + qw*32 + q)*D_MODEL + h*64 + d0);
  dst[0] = r0; dst[1] = r1;
}

// ---------------- launch ----------------
// Workspace lifetimes:
//   [ 0,  8) MB xb   (phases 1-2)  -> pO head  (attn/combine)
//   [ 8, 14) MB wqkv (phases 1-2)  -> pO tail (to 12.6MB) + pML (at 13MB)
//   [14, 16) MB wob  (all phases)
//   [16, 40) MB QKV  (gemm->attn)
//   [40, 48) MB Vtb  (gemm->attn)  -> Of (combine->out-gemm)
extern "C" void kernel_launch(void* const* d_in, const int* in_sizes, int n_in,
                              void* d_out, int out_size, void* d_ws, size_t ws_size,
                              hipStream_t stream) {
  const float* x   = (const float*)d_in[0];
  const int*   pos = (const int*)  d_in[1];
  const float* wq  = (const float*)d_in[2];
  const float* wk  = (const float*)d_in[3];
  const float* wv  = (const float*)d_in[4];
  const float* wo  = (const float*)d_in[5];
  float* out = (float*)d_out;

  char* ws = (char*)d_ws;
  bf16_t* xb   = (bf16_t*)(ws);
  bf16_t* wqkv = (bf16_t*)(ws + ( 8u<<20));
  bf16_t* wob  = (bf16_t*)(ws + (14u<<20));
  bf16_t* QKV  = (bf16_t*)(ws + (16u<<20));
  bf16_t* Vtb  = (bf16_t*)(ws + (40u<<20));
  bf16_t* pO   = (bf16_t*)(ws);                 // 32*96*2048*2B = 12.6 MB
  float2* pML  = (float2*)(ws + (13u<<20));     // 32*96*32*8B = 768 KB
  bf16_t* Of   = (bf16_t*)(ws + (40u<<20));     // overlays dead Vtb

  cvt_x<<<NTOK*D_MODEL/1024, 256, 0, stream>>>(x, xb);
  cvt_w<<<4*D_MODEL*D_MODEL/1024, 256, 0, stream>>>(wq, wk, wv, wo, wqkv, wob);

  dim3 gqkv(NQKV/128, NTOK/128);
  gemm8<bf16_t, true><<<gqkv, 256, 0, stream>>>(xb, wqkv, QKV, Vtb, NTOK, NQKV, D_MODEL);

  rope_qk<<<NTOK*NUM_HEADS*32/256, 256, 0, stream>>>(QKV, pos);

  dim3 gattn(32, 96);
  attn9<<<gattn, 64, 0, stream>>>(QKV, Vtb, pO, pML);

  dim3 gcomb(64, 32);
  combine<<<gcomb, 128, 0, stream>>>(pO, pML, Of);

  dim3 gout(D_MODEL/128, NTOK/128);
  gemm8<float, false><<<gout, 256, 0, stream>>>(Of, wob, out, nullptr, NTOK, D_MODEL, D_MODEL);
}